// Round 4
// baseline (319.938 us; speedup 1.0000x reference)
//
#include <hip/hip_runtime.h>
#include <stdint.h>

#define Bb 2
#define Tt 2048
#define Cc 1024
#define Hh 16
#define HD 64
#define C3 3072

typedef __bf16 bf16x8 __attribute__((ext_vector_type(8)));
typedef float  f32x4  __attribute__((ext_vector_type(4)));
typedef unsigned short u16;
typedef u16 u16x8 __attribute__((ext_vector_type(8)));
typedef u16 u16x4 __attribute__((ext_vector_type(4)));

#define SCALE2 0.18033688f  /* 1/sqrt(64) * log2(e) */

__device__ __forceinline__ u16 f2bf(float f) {
  union { float f; unsigned u; } v; v.f = f;
  return (u16)((v.u + 0x7fffu + ((v.u >> 16) & 1u)) >> 16);  // RNE
}
__device__ __forceinline__ u16 f2bf_fast(float f) {
  union { float f; unsigned u; } v; v.f = f;
  return (u16)((v.u + 0x8000u) >> 16);  // round-half-up, 2 instr
}
__device__ __forceinline__ float bf2f(u16 a) {
  union { unsigned u; float f; } v; v.u = ((unsigned)a) << 16; return v.f;
}

// async global->LDS, 16B per lane (GEMM staging only).
__device__ __forceinline__ void gl2lds16(const void* g, void* s) {
  __builtin_amdgcn_global_load_lds(
      (__attribute__((address_space(1))) void*)(g),
      (__attribute__((address_space(3))) void*)(s), 16, 0, 0);
}

// ---------------- fp32 -> bf16 elementwise ----------------
__global__ void cvt_x_kernel(const float* __restrict__ in, u16* __restrict__ out, int n4) {
  int i = blockIdx.x * blockDim.x + threadIdx.x;
  if (i < n4) {
    float4 v = ((const float4*)in)[i];
    u16x4 o = { f2bf(v.x), f2bf(v.y), f2bf(v.z), f2bf(v.w) };
    ((u16x4*)out)[i] = o;
  }
}

// ---------------- fp32 [R][C] -> bf16 [C][R] tiled transpose ----------------
__global__ void transpose_cvt(const float* __restrict__ in, u16* __restrict__ out,
                              int R, int C) {
  __shared__ u16 tile[64][65];
  int c0 = blockIdx.x * 64, r0 = blockIdx.y * 64;
  int x = threadIdx.x & 63, y = threadIdx.x >> 6;
  #pragma unroll
  for (int rr = y; rr < 64; rr += 4)
    tile[rr][x] = f2bf(in[(size_t)(r0 + rr) * C + c0 + x]);
  __syncthreads();
  #pragma unroll
  for (int rr = y; rr < 64; rr += 4)
    out[(size_t)(c0 + rr) * R + r0 + x] = tile[x][rr];
}

// ---------------- bf16 GEMM: C[M][N] = A[M][K] * Bt[N][K]^T + bias ----------------
template <int MODE>
__global__ __launch_bounds__(256)
void gemm_bt(const u16* __restrict__ A, const u16* __restrict__ Bt,
             const float* __restrict__ bias, void* __restrict__ Cout,
             u16* __restrict__ Vt, int M, int N, int K) {
  __shared__ u16 As[128 * 32];
  __shared__ u16 Bs[128 * 32];
  const int tid = threadIdx.x;
  const int ln  = tid & 63;
  const int w   = tid >> 6;
  const int wm  = w >> 1, wn = w & 1;
  const int l15 = ln & 15, lq = ln >> 4;
  const int m0 = blockIdx.y * 128, n0 = blockIdx.x * 128;

  f32x4 acc[4][4];
  #pragma unroll
  for (int i = 0; i < 4; ++i)
    #pragma unroll
    for (int j = 0; j < 4; ++j)
      acc[i][j] = (f32x4){0.f, 0.f, 0.f, 0.f};

  for (int k0 = 0; k0 < K; k0 += 32) {
    #pragma unroll
    for (int i = 0; i < 2; ++i) {
      int chunk = i * 256 + tid;      // 0..511, 8 bf16 each
      int row = chunk >> 2;           // tile row 0..127
      int cg  = chunk & 3;            // k-group
      gl2lds16(A  + (size_t)(m0 + row) * K + k0 + cg * 8,
               (char*)As + (size_t)(i * 256 + w * 64) * 16);
      gl2lds16(Bt + (size_t)(n0 + row) * K + k0 + cg * 8,
               (char*)Bs + (size_t)(i * 256 + w * 64) * 16);
    }
    __syncthreads();
    bf16x8 af[4], bfr[4];
    #pragma unroll
    for (int i = 0; i < 4; ++i) {
      af[i]  = *(const bf16x8*)&As[(wm * 64 + i * 16 + l15) * 32 + lq * 8];
      bfr[i] = *(const bf16x8*)&Bs[(wn * 64 + i * 16 + l15) * 32 + lq * 8];
    }
    #pragma unroll
    for (int i = 0; i < 4; ++i)
      #pragma unroll
      for (int j = 0; j < 4; ++j)
        acc[i][j] = __builtin_amdgcn_mfma_f32_16x16x32_bf16(af[i], bfr[j], acc[i][j], 0, 0, 0);
    __syncthreads();
  }

  if (MODE == 1 && n0 >= 2048) {
    #pragma unroll
    for (int i = 0; i < 4; ++i) {
      int rowb = m0 + wm * 64 + i * 16 + lq * 4;   // 4 consecutive t
      int b_ = rowb >> 11, t0 = rowb & 2047;
      #pragma unroll
      for (int j = 0; j < 4; ++j) {
        int col = n0 + wn * 64 + j * 16 + l15;
        int hd = col - 2048;
        float bsv = bias[col];
        u16x4 pk;
        #pragma unroll
        for (int r = 0; r < 4; ++r) pk[r] = f2bf(acc[i][j][r] + bsv);
        *(u16x4*)&Vt[(size_t)(b_ * 1024 + hd) * Tt + t0] = pk;
      }
    }
  } else {
    const int ldc = (MODE == 1) ? 2048 : N;
    #pragma unroll
    for (int i = 0; i < 4; ++i) {
      int row = m0 + wm * 64 + i * 16 + lq * 4;
      #pragma unroll
      for (int j = 0; j < 4; ++j) {
        int col = n0 + wn * 64 + j * 16 + l15;
        float bsv = bias[col];
        #pragma unroll
        for (int r = 0; r < 4; ++r) {
          float v = acc[i][j][r] + bsv;
          if (MODE == 1) ((u16*)Cout)[(size_t)(row + r) * ldc + col] = f2bf(v);
          else           ((float*)Cout)[(size_t)(row + r) * ldc + col] = v;
        }
      }
    }
  }
}

// ============ fused causal flash attention — 1 wave/block, prefetched ============
// S^T = K*Q^T: C-layout (col=q, row=kv) repacks in-register into the PV
// A-fragment under the joint kv permutation; V fragments load directly from
// global V^T. One wave per block (64 thr) owns 32 q rows; heavy-first qt map.
// K double-buffered in registers (prefetch next tile before using current).

__device__ __forceinline__ bf16x8 ldb8(const u16* p) {
  return __builtin_bit_cast(bf16x8, *(const u16x8*)p);
}
__device__ __forceinline__ bf16x8 vfrag(const u16* vrow, int c0) {
  u16x4 a = *(const u16x4*)(vrow + c0);
  u16x4 b = *(const u16x4*)(vrow + c0 + 16);
  u16x8 u = { a[0], a[1], a[2], a[3], b[0], b[1], b[2], b[3] };
  return __builtin_bit_cast(bf16x8, u);
}
__device__ __forceinline__ bf16x8 packp(const f32x4& a, const f32x4& b) {
  u16x8 u = { f2bf_fast(a[0]), f2bf_fast(a[1]), f2bf_fast(a[2]), f2bf_fast(a[3]),
              f2bf_fast(b[0]), f2bf_fast(b[1]), f2bf_fast(b[2]), f2bf_fast(b[3]) };
  return __builtin_bit_cast(bf16x8, u);
}
__device__ __forceinline__ bf16x8 qscale(const u16* p) {
  u16x8 q = *(const u16x8*)p;
  u16x8 s;
  #pragma unroll
  for (int j = 0; j < 8; ++j) s[j] = f2bf(bf2f(q[j]) * SCALE2);
  return __builtin_bit_cast(bf16x8, s);
}

__device__ __forceinline__ void softmax_update(
    f32x4 t[4], float& m, float& l, f32x4 o[4],
    int qg, int kk, bool last, int lq, int ln) {
  if (last) {
    #pragma unroll
    for (int i = 0; i < 4; ++i)
      #pragma unroll
      for (int r = 0; r < 4; ++r) {
        int kv = kk + i * 16 + lq * 4 + r;
        if (kv > qg) t[i][r] = -__builtin_inff();
      }
  }
  float mx = t[0][0];
  #pragma unroll
  for (int i = 0; i < 4; ++i)
    #pragma unroll
    for (int r = 0; r < 4; ++r) mx = fmaxf(mx, t[i][r]);
  mx = fmaxf(mx, __shfl_xor(mx, 16));
  mx = fmaxf(mx, __shfl_xor(mx, 32));
  float mn = fmaxf(m, mx);
  float al = __builtin_amdgcn_exp2f(m - mn);
  float ps = 0.f;
  #pragma unroll
  for (int i = 0; i < 4; ++i)
    #pragma unroll
    for (int r = 0; r < 4; ++r) {
      float p = __builtin_amdgcn_exp2f(t[i][r] - mn);
      t[i][r] = p;
      ps += p;
    }
  ps += __shfl_xor(ps, 16);
  ps += __shfl_xor(ps, 32);
  l = l * al + ps;
  m = mn;
  #pragma unroll
  for (int r = 0; r < 4; ++r) {
    float alr = __shfl(al, (ln & 48) + lq * 4 + r, 64);
    #pragma unroll
    for (int jd = 0; jd < 4; ++jd) o[jd][r] *= alr;
  }
}

struct AttnState {
  bf16x8 qA0, qA1, qB0, qB1;
  f32x4 oA[4], oB[4];
  float mA, mB, lA, lB;
};

// one kv-iteration: V loads first, K-prefetch into knxt, QK with kcur, softmax, PV
__device__ __forceinline__ void attn_step(
    AttnState& st, bf16x8 kcur[4][2], bf16x8 knxt[4][2],
    const u16* kbase, const u16* vbase, int kk, int kkn,
    int q0, bool last, int l15, int lq, int ln) {
  // V fragments for current tile (early issue; consumed after softmax)
  bf16x8 vf[4][2];
  #pragma unroll
  for (int jd = 0; jd < 4; ++jd) {
    const u16* vr = vbase + (size_t)(jd * 16 + l15) * Tt;
    vf[jd][0] = vfrag(vr, kk + lq * 4);
    vf[jd][1] = vfrag(vr, kk + 32 + lq * 4);
  }
  // prefetch next K tile
  #pragma unroll
  for (int i = 0; i < 4; ++i) {
    const u16* kr = kbase + (size_t)(kkn + i * 16 + l15) * 2048;
    knxt[i][0] = ldb8(kr + lq * 8);
    knxt[i][1] = ldb8(kr + 32 + lq * 8);
  }
  // S^T = K * Q^T
  f32x4 tA[4], tB[4];
  #pragma unroll
  for (int i = 0; i < 4; ++i) { tA[i] = (f32x4){0,0,0,0}; tB[i] = (f32x4){0,0,0,0}; }
  #pragma unroll
  for (int i = 0; i < 4; ++i) {
    tA[i] = __builtin_amdgcn_mfma_f32_16x16x32_bf16(kcur[i][0], st.qA0, tA[i], 0, 0, 0);
    tA[i] = __builtin_amdgcn_mfma_f32_16x16x32_bf16(kcur[i][1], st.qA1, tA[i], 0, 0, 0);
    tB[i] = __builtin_amdgcn_mfma_f32_16x16x32_bf16(kcur[i][0], st.qB0, tB[i], 0, 0, 0);
    tB[i] = __builtin_amdgcn_mfma_f32_16x16x32_bf16(kcur[i][1], st.qB1, tB[i], 0, 0, 0);
  }
  softmax_update(tA, st.mA, st.lA, st.oA, q0 + l15,      kk, last, lq, ln);
  softmax_update(tB, st.mB, st.lB, st.oB, q0 + 16 + l15, kk, last, lq, ln);

  bf16x8 pA0 = packp(tA[0], tA[1]), pA1 = packp(tA[2], tA[3]);
  bf16x8 pB0 = packp(tB[0], tB[1]), pB1 = packp(tB[2], tB[3]);

  #pragma unroll
  for (int jd = 0; jd < 4; ++jd) {
    st.oA[jd] = __builtin_amdgcn_mfma_f32_16x16x32_bf16(pA0, vf[jd][0], st.oA[jd], 0, 0, 0);
    st.oA[jd] = __builtin_amdgcn_mfma_f32_16x16x32_bf16(pA1, vf[jd][1], st.oA[jd], 0, 0, 0);
    st.oB[jd] = __builtin_amdgcn_mfma_f32_16x16x32_bf16(pB0, vf[jd][0], st.oB[jd], 0, 0, 0);
    st.oB[jd] = __builtin_amdgcn_mfma_f32_16x16x32_bf16(pB1, vf[jd][1], st.oB[jd], 0, 0, 0);
  }
}

__global__ __launch_bounds__(64, 3)
void attn_fused(const u16* __restrict__ qk, const u16* __restrict__ vt,
                u16* __restrict__ y) {
  const int ln = threadIdx.x & 63;
  const int l15 = ln & 15, lq = ln >> 4;
  const int bx = blockIdx.x;
  const int bh = bx & 31;            // (b,h)
  const int h  = bh & 15, b = bh >> 4;
  const int qt = 63 - (bx >> 5);     // heavy tiles dispatched first
  const int q0 = qt * 32;

  const u16* qbase = qk + (size_t)(b * Tt) * 2048 + h * HD;
  const u16* kbase = qk + (size_t)(b * Tt) * 2048 + 1024 + h * HD;
  const u16* vbase = vt + (size_t)(b * 1024 + h * HD) * Tt;

  AttnState st;
  // Q B-fragments (n=q, k=d), prescaled by 1/sqrt(d)*log2e
  const u16* qrA = qbase + (size_t)(q0 + l15) * 2048;
  const u16* qrB = qbase + (size_t)(q0 + 16 + l15) * 2048;
  st.qA0 = qscale(qrA + lq * 8); st.qA1 = qscale(qrA + 32 + lq * 8);
  st.qB0 = qscale(qrB + lq * 8); st.qB1 = qscale(qrB + 32 + lq * 8);
  #pragma unroll
  for (int j = 0; j < 4; ++j) { st.oA[j] = (f32x4){0,0,0,0}; st.oB[j] = (f32x4){0,0,0,0}; }
  st.mA = -__builtin_inff(); st.mB = -__builtin_inff();
  st.lA = 0.f; st.lB = 0.f;

  const int nkv = (qt >> 1) + 1;

  // preload K tile 0
  bf16x8 kb0[4][2], kb1[4][2];
  #pragma unroll
  for (int i = 0; i < 4; ++i) {
    const u16* kr = kbase + (size_t)(i * 16 + l15) * 2048;
    kb0[i][0] = ldb8(kr + lq * 8);
    kb0[i][1] = ldb8(kr + 32 + lq * 8);
  }

  int it = 0;
  while (true) {
    {
      int kk = it * 64;
      bool lastI = (it == nkv - 1);
      int kkn = lastI ? kk : kk + 64;
      attn_step(st, kb0, kb1, kbase, vbase, kk, kkn, q0, lastI, l15, lq, ln);
      if (++it == nkv) break;
    }
    {
      int kk = it * 64;
      bool lastI = (it == nkv - 1);
      int kkn = lastI ? kk : kk + 64;
      attn_step(st, kb1, kb0, kbase, vbase, kk, kkn, q0, lastI, l15, lq, ln);
      if (++it == nkv) break;
    }
  }

  // epilogue: normalize (redistribute 1/l from col-lanes to row-lanes) + store
  float ivA = 1.f / st.lA, ivB = 1.f / st.lB;
  #pragma unroll
  for (int r = 0; r < 4; ++r) {
    float iAr = __shfl(ivA, (ln & 48) + lq * 4 + r, 64);
    float iBr = __shfl(ivB, (ln & 48) + lq * 4 + r, 64);
    int rowA = q0 + lq * 4 + r, rowB = rowA + 16;
    #pragma unroll
    for (int jd = 0; jd < 4; ++jd) {
      y[(size_t)(b * Tt + rowA) * Cc + h * HD + jd * 16 + l15] = f2bf(st.oA[jd][r] * iAr);
      y[(size_t)(b * Tt + rowB) * Cc + h * HD + jd * 16 + l15] = f2bf(st.oB[jd][r] * iBr);
    }
  }
}

extern "C" void kernel_launch(void* const* d_in, const int* in_sizes, int n_in,
                              void* d_out, int out_size, void* d_ws, size_t ws_size,
                              hipStream_t stream) {
  const float* x      = (const float*)d_in[0];
  const float* w_attn = (const float*)d_in[1];
  const float* b_attn = (const float*)d_in[2];
  const float* w_proj = (const float*)d_in[3];
  const float* b_proj = (const float*)d_in[4];
  float* out = (float*)d_out;

  char* ws = (char*)d_ws;
  u16* xb  = (u16*)(ws + 0);          // 4096x1024 bf16   (8 MB)
  u16* wat = (u16*)(ws + 8388608);    // 3072x1024 bf16   (6 MB)   w_attn^T
  u16* wpt = (u16*)(ws + 14680064);   // 1024x1024 bf16   (2 MB)   w_proj^T
  u16* qkb = (u16*)(ws + 16777216);   // 4096x2048 bf16   (16 MB)  Q,K
  u16* vtb = (u16*)(ws + 33554432);   // 2048x2048 bf16   (8 MB)   V^T per (b,h)
  u16* yb  = (u16*)(ws + 41943040);   // 4096x1024 bf16   (8 MB)

  cvt_x_kernel<<<4096, 256, 0, stream>>>(x, xb, 1048576);
  transpose_cvt<<<dim3(48, 16), 256, 0, stream>>>(w_attn, wat, 1024, 3072);
  transpose_cvt<<<dim3(16, 16), 256, 0, stream>>>(w_proj, wpt, 1024, 1024);
  gemm_bt<1><<<dim3(24, 32), 256, 0, stream>>>(xb, wat, b_attn, (void*)qkb, vtb, 4096, 3072, 1024);
  attn_fused<<<2048, 64, 0, stream>>>(qkb, vtb, yb);
  gemm_bt<0><<<dim3(8, 32), 256, 0, stream>>>(yb, wpt, b_proj, (void*)out, nullptr, 4096, 1024, 1024);
}

// Round 5
// 305.853 us; speedup vs baseline: 1.0461x; 1.0461x over previous
//
#include <hip/hip_runtime.h>
#include <stdint.h>

#define Bb 2
#define Tt 2048
#define Cc 1024
#define Hh 16
#define HD 64
#define C3 3072

typedef __bf16 bf16x8 __attribute__((ext_vector_type(8)));
typedef float  f32x4  __attribute__((ext_vector_type(4)));
typedef unsigned short u16;
typedef u16 u16x8 __attribute__((ext_vector_type(8)));
typedef u16 u16x4 __attribute__((ext_vector_type(4)));

#define SCALE2 0.18033688f  /* 1/sqrt(64) * log2(e) */

__device__ __forceinline__ u16 f2bf(float f) {
  union { float f; unsigned u; } v; v.f = f;
  return (u16)((v.u + 0x7fffu + ((v.u >> 16) & 1u)) >> 16);  // RNE
}
__device__ __forceinline__ u16 f2bf_fast(float f) {
  union { float f; unsigned u; } v; v.f = f;
  return (u16)((v.u + 0x8000u) >> 16);  // round-half-up, 2 instr
}
__device__ __forceinline__ float bf2f(u16 a) {
  union { unsigned u; float f; } v; v.u = ((unsigned)a) << 16; return v.f;
}

// async global->LDS, 16B per lane (GEMM staging only).
__device__ __forceinline__ void gl2lds16(const void* g, void* s) {
  __builtin_amdgcn_global_load_lds(
      (__attribute__((address_space(1))) void*)(g),
      (__attribute__((address_space(3))) void*)(s), 16, 0, 0);
}

// ---------------- fp32 -> bf16 elementwise ----------------
__global__ void cvt_x_kernel(const float* __restrict__ in, u16* __restrict__ out, int n4) {
  int i = blockIdx.x * blockDim.x + threadIdx.x;
  if (i < n4) {
    float4 v = ((const float4*)in)[i];
    u16x4 o = { f2bf(v.x), f2bf(v.y), f2bf(v.z), f2bf(v.w) };
    ((u16x4*)out)[i] = o;
  }
}

// ---------------- fp32 [R][C] -> bf16 [C][R] tiled transpose ----------------
__global__ void transpose_cvt(const float* __restrict__ in, u16* __restrict__ out,
                              int R, int C) {
  __shared__ u16 tile[64][65];
  int c0 = blockIdx.x * 64, r0 = blockIdx.y * 64;
  int x = threadIdx.x & 63, y = threadIdx.x >> 6;
  #pragma unroll
  for (int rr = y; rr < 64; rr += 4)
    tile[rr][x] = f2bf(in[(size_t)(r0 + rr) * C + c0 + x]);
  __syncthreads();
  #pragma unroll
  for (int rr = y; rr < 64; rr += 4)
    out[(size_t)(c0 + rr) * R + r0 + x] = tile[x][rr];
}

// ---------------- bf16 GEMM: C[M][N] = A[M][K] * Bt[N][K]^T + bias ----------------
template <int MODE>
__global__ __launch_bounds__(256)
void gemm_bt(const u16* __restrict__ A, const u16* __restrict__ Bt,
             const float* __restrict__ bias, void* __restrict__ Cout,
             u16* __restrict__ Vt, int M, int N, int K) {
  __shared__ u16 As[128 * 32];
  __shared__ u16 Bs[128 * 32];
  const int tid = threadIdx.x;
  const int ln  = tid & 63;
  const int w   = tid >> 6;
  const int wm  = w >> 1, wn = w & 1;
  const int l15 = ln & 15, lq = ln >> 4;
  const int m0 = blockIdx.y * 128, n0 = blockIdx.x * 128;

  f32x4 acc[4][4];
  #pragma unroll
  for (int i = 0; i < 4; ++i)
    #pragma unroll
    for (int j = 0; j < 4; ++j)
      acc[i][j] = (f32x4){0.f, 0.f, 0.f, 0.f};

  for (int k0 = 0; k0 < K; k0 += 32) {
    #pragma unroll
    for (int i = 0; i < 2; ++i) {
      int chunk = i * 256 + tid;      // 0..511, 8 bf16 each
      int row = chunk >> 2;           // tile row 0..127
      int cg  = chunk & 3;            // k-group
      gl2lds16(A  + (size_t)(m0 + row) * K + k0 + cg * 8,
               (char*)As + (size_t)(i * 256 + w * 64) * 16);
      gl2lds16(Bt + (size_t)(n0 + row) * K + k0 + cg * 8,
               (char*)Bs + (size_t)(i * 256 + w * 64) * 16);
    }
    __syncthreads();
    bf16x8 af[4], bfr[4];
    #pragma unroll
    for (int i = 0; i < 4; ++i) {
      af[i]  = *(const bf16x8*)&As[(wm * 64 + i * 16 + l15) * 32 + lq * 8];
      bfr[i] = *(const bf16x8*)&Bs[(wn * 64 + i * 16 + l15) * 32 + lq * 8];
    }
    #pragma unroll
    for (int i = 0; i < 4; ++i)
      #pragma unroll
      for (int j = 0; j < 4; ++j)
        acc[i][j] = __builtin_amdgcn_mfma_f32_16x16x32_bf16(af[i], bfr[j], acc[i][j], 0, 0, 0);
    __syncthreads();
  }

  if (MODE == 1 && n0 >= 2048) {
    #pragma unroll
    for (int i = 0; i < 4; ++i) {
      int rowb = m0 + wm * 64 + i * 16 + lq * 4;   // 4 consecutive t
      int b_ = rowb >> 11, t0 = rowb & 2047;
      #pragma unroll
      for (int j = 0; j < 4; ++j) {
        int col = n0 + wn * 64 + j * 16 + l15;
        int hd = col - 2048;
        float bsv = bias[col];
        u16x4 pk;
        #pragma unroll
        for (int r = 0; r < 4; ++r) pk[r] = f2bf(acc[i][j][r] + bsv);
        *(u16x4*)&Vt[(size_t)(b_ * 1024 + hd) * Tt + t0] = pk;
      }
    }
  } else {
    const int ldc = (MODE == 1) ? 2048 : N;
    #pragma unroll
    for (int i = 0; i < 4; ++i) {
      int row = m0 + wm * 64 + i * 16 + lq * 4;
      #pragma unroll
      for (int j = 0; j < 4; ++j) {
        int col = n0 + wn * 64 + j * 16 + l15;
        float bsv = bias[col];
        #pragma unroll
        for (int r = 0; r < 4; ++r) {
          float v = acc[i][j][r] + bsv;
          if (MODE == 1) ((u16*)Cout)[(size_t)(row + r) * ldc + col] = f2bf(v);
          else           ((float*)Cout)[(size_t)(row + r) * ldc + col] = v;
        }
      }
    }
  }
}

// ============ fused causal flash attention — split-kv, 2 waves/block ============
// S^T = K*Q^T: C-layout (col=q, row=kv) repacks in-register into the PV
// A-fragment under the joint kv permutation; V fragments load directly from
// global V^T. Block = 128 thr = 2 waves; both waves own the same 32 q rows,
// wave 0 takes even kv tiles, wave 1 odd. Combine via LDS + one barrier.
// K processed in d-halves (16 regs), V in kv-halves (16 regs) -> peak ~110 VGPR.

__device__ __forceinline__ bf16x8 ldb8(const u16* p) {
  return __builtin_bit_cast(bf16x8, *(const u16x8*)p);
}
__device__ __forceinline__ bf16x8 vfrag(const u16* vrow, int c0) {
  u16x4 a = *(const u16x4*)(vrow + c0);
  u16x4 b = *(const u16x4*)(vrow + c0 + 16);
  u16x8 u = { a[0], a[1], a[2], a[3], b[0], b[1], b[2], b[3] };
  return __builtin_bit_cast(bf16x8, u);
}
__device__ __forceinline__ bf16x8 packp(const f32x4& a, const f32x4& b) {
  u16x8 u = { f2bf_fast(a[0]), f2bf_fast(a[1]), f2bf_fast(a[2]), f2bf_fast(a[3]),
              f2bf_fast(b[0]), f2bf_fast(b[1]), f2bf_fast(b[2]), f2bf_fast(b[3]) };
  return __builtin_bit_cast(bf16x8, u);
}
__device__ __forceinline__ bf16x8 qscale(const u16* p) {
  u16x8 q = *(const u16x8*)p;
  u16x8 s;
  #pragma unroll
  for (int j = 0; j < 8; ++j) s[j] = f2bf(bf2f(q[j]) * SCALE2);
  return __builtin_bit_cast(bf16x8, s);
}

__device__ __forceinline__ void softmax_update(
    f32x4 t[4], float& m, float& l, f32x4 o[4],
    int qg, int kk, bool last, int lq, int ln) {
  if (last) {
    #pragma unroll
    for (int i = 0; i < 4; ++i)
      #pragma unroll
      for (int r = 0; r < 4; ++r) {
        int kv = kk + i * 16 + lq * 4 + r;
        if (kv > qg) t[i][r] = -__builtin_inff();
      }
  }
  float mx = t[0][0];
  #pragma unroll
  for (int i = 0; i < 4; ++i)
    #pragma unroll
    for (int r = 0; r < 4; ++r) mx = fmaxf(mx, t[i][r]);
  mx = fmaxf(mx, __shfl_xor(mx, 16));
  mx = fmaxf(mx, __shfl_xor(mx, 32));
  float mn = fmaxf(m, mx);
  float al = __builtin_amdgcn_exp2f(m - mn);
  float ps = 0.f;
  #pragma unroll
  for (int i = 0; i < 4; ++i)
    #pragma unroll
    for (int r = 0; r < 4; ++r) {
      float p = __builtin_amdgcn_exp2f(t[i][r] - mn);
      t[i][r] = p;
      ps += p;
    }
  ps += __shfl_xor(ps, 16);
  ps += __shfl_xor(ps, 32);
  l = l * al + ps;
  m = mn;
  #pragma unroll
  for (int r = 0; r < 4; ++r) {
    float alr = __shfl(al, (ln & 48) + lq * 4 + r, 64);
    #pragma unroll
    for (int jd = 0; jd < 4; ++jd) o[jd][r] *= alr;
  }
}

__global__ __launch_bounds__(128, 4)
void attn_fused(const u16* __restrict__ qk, const u16* __restrict__ vt,
                u16* __restrict__ y) {
  __shared__ float ocomb[32 * 68];   // wave-1 partial O, padded stride 68
  __shared__ float mlcomb[64];       // m[0..31], l[32..63]
  const int tid = threadIdx.x;
  const int ln = tid & 63, w = tid >> 6;
  const int l15 = ln & 15, lq = ln >> 4;
  const int bx = blockIdx.x;
  const int bh = bx & 31;            // (b,h)
  const int h  = bh & 15, b = bh >> 4;
  const int qt = 63 - (bx >> 5);     // heavy tiles dispatched first
  const int q0 = qt * 32;

  const u16* qbase = qk + (size_t)(b * Tt) * 2048 + h * HD;
  const u16* kbase = qk + (size_t)(b * Tt) * 2048 + 1024 + h * HD;
  const u16* vbase = vt + (size_t)(b * 1024 + h * HD) * Tt;

  // Q B-fragments (n=q, k=d), prescaled by 1/sqrt(d)*log2e
  const u16* qrA = qbase + (size_t)(q0 + l15) * 2048;
  const u16* qrB = qbase + (size_t)(q0 + 16 + l15) * 2048;
  bf16x8 qA0 = qscale(qrA + lq * 8), qA1 = qscale(qrA + 32 + lq * 8);
  bf16x8 qB0 = qscale(qrB + lq * 8), qB1 = qscale(qrB + 32 + lq * 8);

  f32x4 oA[4], oB[4];
  #pragma unroll
  for (int j = 0; j < 4; ++j) { oA[j] = (f32x4){0,0,0,0}; oB[j] = (f32x4){0,0,0,0}; }
  float mA = -__builtin_inff(), mB = -__builtin_inff();
  float lA = 0.f, lB = 0.f;

  const int nkv = (qt >> 1) + 1;

  for (int it = w; it < nkv; it += 2) {
    const int kk = it * 64;
    const bool lastI = (it == nkv - 1);

    // S^T = K * Q^T, K in d-halves (16 regs live)
    f32x4 tA[4], tB[4];
    #pragma unroll
    for (int i = 0; i < 4; ++i) { tA[i] = (f32x4){0,0,0,0}; tB[i] = (f32x4){0,0,0,0}; }
    bf16x8 kf[4];
    #pragma unroll
    for (int i = 0; i < 4; ++i)
      kf[i] = ldb8(kbase + (size_t)(kk + i * 16 + l15) * 2048 + lq * 8);
    #pragma unroll
    for (int i = 0; i < 4; ++i) {
      tA[i] = __builtin_amdgcn_mfma_f32_16x16x32_bf16(kf[i], qA0, tA[i], 0, 0, 0);
      tB[i] = __builtin_amdgcn_mfma_f32_16x16x32_bf16(kf[i], qB0, tB[i], 0, 0, 0);
    }
    #pragma unroll
    for (int i = 0; i < 4; ++i)
      kf[i] = ldb8(kbase + (size_t)(kk + i * 16 + l15) * 2048 + 32 + lq * 8);
    #pragma unroll
    for (int i = 0; i < 4; ++i) {
      tA[i] = __builtin_amdgcn_mfma_f32_16x16x32_bf16(kf[i], qA1, tA[i], 0, 0, 0);
      tB[i] = __builtin_amdgcn_mfma_f32_16x16x32_bf16(kf[i], qB1, tB[i], 0, 0, 0);
    }

    // V first kv-half: issue early, consumed after softmax
    bf16x8 vf[4];
    #pragma unroll
    for (int jd = 0; jd < 4; ++jd)
      vf[jd] = vfrag(vbase + (size_t)(jd * 16 + l15) * Tt, kk + lq * 4);

    softmax_update(tA, mA, lA, oA, q0 + l15,      kk, lastI, lq, ln);
    softmax_update(tB, mB, lB, oB, q0 + 16 + l15, kk, lastI, lq, ln);

    bf16x8 pA0 = packp(tA[0], tA[1]), pA1 = packp(tA[2], tA[3]);
    bf16x8 pB0 = packp(tB[0], tB[1]), pB1 = packp(tB[2], tB[3]);

    #pragma unroll
    for (int jd = 0; jd < 4; ++jd) {
      oA[jd] = __builtin_amdgcn_mfma_f32_16x16x32_bf16(pA0, vf[jd], oA[jd], 0, 0, 0);
      oB[jd] = __builtin_amdgcn_mfma_f32_16x16x32_bf16(pB0, vf[jd], oB[jd], 0, 0, 0);
    }
    #pragma unroll
    for (int jd = 0; jd < 4; ++jd)
      vf[jd] = vfrag(vbase + (size_t)(jd * 16 + l15) * Tt, kk + 32 + lq * 4);
    #pragma unroll
    for (int jd = 0; jd < 4; ++jd) {
      oA[jd] = __builtin_amdgcn_mfma_f32_16x16x32_bf16(pA1, vf[jd], oA[jd], 0, 0, 0);
      oB[jd] = __builtin_amdgcn_mfma_f32_16x16x32_bf16(pB1, vf[jd], oB[jd], 0, 0, 0);
    }
  }

  // ---- combine the two waves' partial (m, l, o) ----
  if (w == 1) {
    #pragma unroll
    for (int r = 0; r < 4; ++r)
      #pragma unroll
      for (int jd = 0; jd < 4; ++jd) {
        ocomb[(lq * 4 + r) * 68 + jd * 16 + l15]      = oA[jd][r];
        ocomb[(16 + lq * 4 + r) * 68 + jd * 16 + l15] = oB[jd][r];
      }
    if (lq == 0) {
      mlcomb[l15]      = mA;
      mlcomb[16 + l15] = mB;
      mlcomb[32 + l15] = lA;
      mlcomb[48 + l15] = lB;
    }
  }
  __syncthreads();
  if (w == 0) {
    #pragma unroll
    for (int r = 0; r < 4; ++r) {
      int rA = lq * 4 + r, rB = 16 + rA;
      float m1A = mlcomb[rA],      l1A = mlcomb[32 + rA];
      float m1B = mlcomb[16 + rA], l1B = mlcomb[48 + rA];
      float m0A = __shfl(mA, (ln & 48) + rA, 64);
      float l0A = __shfl(lA, (ln & 48) + rA, 64);
      float m0B = __shfl(mB, (ln & 48) + rA, 64);
      float l0B = __shfl(lB, (ln & 48) + rA, 64);
      float msA = fmaxf(m0A, m1A);
      float a0A = __builtin_amdgcn_exp2f(m0A - msA);
      float a1A = __builtin_amdgcn_exp2f(m1A - msA);
      float invA = 1.f / (l0A * a0A + l1A * a1A);
      float msB = fmaxf(m0B, m1B);
      float a0B = __builtin_amdgcn_exp2f(m0B - msB);
      float a1B = __builtin_amdgcn_exp2f(m1B - msB);
      float invB = 1.f / (l0B * a0B + l1B * a1B);
      int rowA = q0 + rA, rowB = q0 + rB;
      #pragma unroll
      for (int jd = 0; jd < 4; ++jd) {
        float vA = (oA[jd][r] * a0A + ocomb[rA * 68 + jd * 16 + l15] * a1A) * invA;
        float vB = (oB[jd][r] * a0B + ocomb[rB * 68 + jd * 16 + l15] * a1B) * invB;
        y[(size_t)(b * Tt + rowA) * Cc + h * HD + jd * 16 + l15] = f2bf(vA);
        y[(size_t)(b * Tt + rowB) * Cc + h * HD + jd * 16 + l15] = f2bf(vB);
      }
    }
  }
}

extern "C" void kernel_launch(void* const* d_in, const int* in_sizes, int n_in,
                              void* d_out, int out_size, void* d_ws, size_t ws_size,
                              hipStream_t stream) {
  const float* x      = (const float*)d_in[0];
  const float* w_attn = (const float*)d_in[1];
  const float* b_attn = (const float*)d_in[2];
  const float* w_proj = (const float*)d_in[3];
  const float* b_proj = (const float*)d_in[4];
  float* out = (float*)d_out;

  char* ws = (char*)d_ws;
  u16* xb  = (u16*)(ws + 0);          // 4096x1024 bf16   (8 MB)
  u16* wat = (u16*)(ws + 8388608);    // 3072x1024 bf16   (6 MB)   w_attn^T
  u16* wpt = (u16*)(ws + 14680064);   // 1024x1024 bf16   (2 MB)   w_proj^T
  u16* qkb = (u16*)(ws + 16777216);   // 4096x2048 bf16   (16 MB)  Q,K
  u16* vtb = (u16*)(ws + 33554432);   // 2048x2048 bf16   (8 MB)   V^T per (b,h)
  u16* yb  = (u16*)(ws + 41943040);   // 4096x1024 bf16   (8 MB)

  cvt_x_kernel<<<4096, 256, 0, stream>>>(x, xb, 1048576);
  transpose_cvt<<<dim3(48, 16), 256, 0, stream>>>(w_attn, wat, 1024, 3072);
  transpose_cvt<<<dim3(16, 16), 256, 0, stream>>>(w_proj, wpt, 1024, 1024);
  gemm_bt<1><<<dim3(24, 32), 256, 0, stream>>>(xb, wat, b_attn, (void*)qkb, vtb, 4096, 3072, 1024);
  attn_fused<<<2048, 128, 0, stream>>>(qkb, vtb, yb);
  gemm_bt<0><<<dim3(8, 32), 256, 0, stream>>>(yb, wpt, b_proj, (void*)out, nullptr, 4096, 1024, 1024);
}